// Round 4
// baseline (1344.182 us; speedup 1.0000x reference)
//
#include <hip/hip_runtime.h>
#include <hip/hip_bf16.h>

// Fused InverseResNet: h = x@Wi+bi; 4x{10x fixed-point y-(relu(xW1+b1)W2+b2)}; out = x@Wf+bf
// Round 4: (a) pin 2 waves/EU -> 256-reg budget (R3's heuristic clamp to 128 caused
// 1.6 GB spill traffic); (b) swapped MFMA operands: weights = A (registers, same bits
// as before), activations = B (LDS row-major, same b128 reads), acc = C^T so each lane
// writes 4-col quads -> ds_write_b64 instead of 64x ds_write_b16. W2 negated, b2 folded
// into yreg at block start, b1 as per-reg f32x16. ~210 VGPR/lane -> no spill.

#define B_TOTAL 65536
#define LATENT  128
#define HIDDEN  256
#define OUTD    128
#define NBLOCKS 4
#define NITER   10
#define MTILE   64
#define LDSP    264   // row stride (elems); 528 B rows: 16B-aligned, b128 conflict-free

typedef unsigned short u16;
typedef u16    u16x4  __attribute__((ext_vector_type(4)));
typedef u16    u16x8  __attribute__((ext_vector_type(8)));
typedef __bf16 bf16x8 __attribute__((ext_vector_type(8)));
typedef float  f32x16 __attribute__((ext_vector_type(16)));

__device__ inline u16 f2b(float f){
  __bf16 h = (__bf16)f;
  return __builtin_bit_cast(u16, h);
}

// Weight fragment (A-operand = W^T): lane lo holds W[k][col], k = krow0 + j.
// Identical bits to the old B-fragment. neg=true -> -W (exact sign flip).
__device__ inline bf16x8 load_wfrag_f(const float* __restrict__ W, int ldw, int krow0,
                                      int col, bool neg){
  bf16x8 r;
#pragma unroll
  for (int j=0;j<8;j++){
    float v = W[(size_t)(krow0+j)*ldw + col];
    r[j] = (__bf16)(neg ? -v : v);
  }
  return r;
}

// Per-reg bias vector: b[col(r)] for C^T layout, col(r) = nb + (r&3) + 8*(r>>2) + 4*hi
__device__ inline f32x16 load_bias(const float* __restrict__ b, int nb, int hi){
  f32x16 v;
#pragma unroll
  for (int r=0;r<16;r++) v[r] = b[nb + (r&3) + 8*(r>>2) + 4*hi];
  return v;
}

// Store one C^T tile (16 vals) to LDS row-major [64 x LDSP]: row = rowbase(+lo),
// cols = nb + 8q + 4hi + {0..3}  -> 4x ds_write_b64
__device__ inline void store_tile(u16* __restrict__ dst, int row_elem, int nb, int hi,
                                  const f32x16 a, bool relu){
#pragma unroll
  for (int q=0;q<4;q++){
    u16x4 p;
#pragma unroll
    for (int i=0;i<4;i++){
      float v = a[4*q+i];
      if (relu) v = v > 0.f ? v : 0.f;
      p[i] = f2b(v);
    }
    *(u16x4*)(dst + row_elem + nb + 8*q + 4*hi) = p;
  }
}

// D = A*B + C, A = weights (regs), B = activations (LDS)
#define MFMA(a,b,c) __builtin_amdgcn_mfma_f32_32x32x16_bf16(a,b,c,0,0,0)

__global__
__attribute__((amdgpu_flat_work_group_size(512,512)))
__attribute__((amdgpu_waves_per_eu(2,2)))
void irn_kernel(const float* __restrict__ x,
                const float* __restrict__ Winit, const float* __restrict__ binit,
                const float* __restrict__ Wg1,   const float* __restrict__ bg1,
                const float* __restrict__ Wg2,   const float* __restrict__ bg2,
                const float* __restrict__ Wfin,  const float* __restrict__ bfin,
                float* __restrict__ out)
{
  __shared__ u16 Xb[MTILE*LDSP];
  __shared__ u16 Hb[MTILE*LDSP];

  const int tid = threadIdx.x;
  const int wv  = tid >> 6;      // wave 0..7 -> 32-col slice of HIDDEN (weight cols)
  const int ln  = tid & 63;
  const int lo  = ln & 31;
  const int hi  = ln >> 5;
  const int row0 = blockIdx.x * MTILE;
  const int nb   = wv * 32;

  // ---- stage x tile [64 x 128] fp32 -> bf16 into Xb (row-major) ----
  {
    const int r  = tid >> 3;          // 0..63
    const int c0 = (tid & 7) * 16;    // col chunk of 16
    const float4* src = (const float4*)(x + (size_t)(row0 + r)*LATENT + c0);
    u16x8 p0, p1;
#pragma unroll
    for (int i=0;i<2;i++){
      float4 a = src[i*2], b = src[i*2+1];
      u16x8& p = i ? p1 : p0;
      p[0]=f2b(a.x); p[1]=f2b(a.y); p[2]=f2b(a.z); p[3]=f2b(a.w);
      p[4]=f2b(b.x); p[5]=f2b(b.y); p[6]=f2b(b.z); p[7]=f2b(b.w);
    }
    u16* dst = Xb + r*LDSP + c0;
    *(u16x8*)(dst)   = p0;
    *(u16x8*)(dst+8) = p1;
  }

  // B-fragment (activation) read bases, elements: rows nt*32+lo, k-chunk hi*8
  const int rdA0 = lo*LDSP + hi*8;
  const int rdA1 = (32+lo)*LDSP + hi*8;

  f32x16 yreg[2];   // y - b2 for this wave's [rows 0..63] x [cols nb..nb+31], C^T layout

  __syncthreads();

  // ---- initial GEMM: h^T = Winit^T @ x^T  (K=128) ----
  {
    bf16x8 wf[8];
#pragma unroll
    for (int ks=0; ks<8; ks++)
      wf[ks] = load_wfrag_f(Winit, HIDDEN, ks*16 + hi*8, nb + lo, false);
    const f32x16 bi = load_bias(binit, nb, hi);
    f32x16 acc[2];
    acc[0]=bi; acc[1]=bi;
#pragma unroll
    for (int ks=0; ks<8; ks++){
      bf16x8 b0 = *(const bf16x8*)(Xb + rdA0 + ks*16);
      bf16x8 b1 = *(const bf16x8*)(Xb + rdA1 + ks*16);
      acc[0]=MFMA(wf[ks], b0, acc[0]);
      acc[1]=MFMA(wf[ks], b1, acc[1]);
    }
    __syncthreads();   // all reads of Xb done before overwrite
    store_tile(Xb, (0 +lo)*LDSP, nb, hi, acc[0], false);
    store_tile(Xb, (32+lo)*LDSP, nb, hi, acc[1], false);
    yreg[0]=acc[0]; yreg[1]=acc[1];
    __syncthreads();
  }

  // ---- 4 blocks x 10 fixed-point iterations ----
#pragma unroll 1
  for (int b=0; b<NBLOCKS; b++){
    const float* W1 = Wg1 + (size_t)b*HIDDEN*HIDDEN;
    const float* W2 = Wg2 + (size_t)b*HIDDEN*HIDDEN;
    bf16x8 w1f[16], w2f[16];
#pragma unroll
    for (int ks=0; ks<16; ks++){
      w1f[ks] = load_wfrag_f(W1, HIDDEN, ks*16 + hi*8, nb + lo, false);
      w2f[ks] = load_wfrag_f(W2, HIDDEN, ks*16 + hi*8, nb + lo, true); // -W2
    }
    const f32x16 b1v = load_bias(bg1 + b*HIDDEN, nb, hi);
    { // fold b2 into y once per block: yreg <- y - b2
      const f32x16 b2v = load_bias(bg2 + b*HIDDEN, nb, hi);
      yreg[0] = yreg[0] - b2v;
      yreg[1] = yreg[1] - b2v;
    }

#pragma unroll 1
    for (int it=0; it<NITER; it++){
      { // phase 1: H = relu(X @ W1 + b1)   (computed as C^T)
        f32x16 acc[2];
        acc[0]=b1v; acc[1]=b1v;
#pragma unroll
        for (int ks=0; ks<16; ks++){
          bf16x8 b0 = *(const bf16x8*)(Xb + rdA0 + ks*16);
          bf16x8 b1 = *(const bf16x8*)(Xb + rdA1 + ks*16);
          acc[0]=MFMA(w1f[ks], b0, acc[0]);
          acc[1]=MFMA(w1f[ks], b1, acc[1]);
        }
        store_tile(Hb, (0 +lo)*LDSP, nb, hi, acc[0], true);
        store_tile(Hb, (32+lo)*LDSP, nb, hi, acc[1], true);
      }
      __syncthreads();
      { // phase 2: Xnew = (y - b2) + H @ (-W2)
        f32x16 acc[2];
        acc[0]=yreg[0]; acc[1]=yreg[1];
#pragma unroll
        for (int ks=0; ks<16; ks++){
          bf16x8 b0 = *(const bf16x8*)(Hb + rdA0 + ks*16);
          bf16x8 b1 = *(const bf16x8*)(Hb + rdA1 + ks*16);
          acc[0]=MFMA(w2f[ks], b0, acc[0]);
          acc[1]=MFMA(w2f[ks], b1, acc[1]);
        }
        store_tile(Xb, (0 +lo)*LDSP, nb, hi, acc[0], false);
        store_tile(Xb, (32+lo)*LDSP, nb, hi, acc[1], false);
        if (it == NITER-1){ yreg[0]=acc[0]; yreg[1]=acc[1]; } // new y (pre b2-fold)
      }
      __syncthreads();
    }
  }

  // ---- final GEMM: out^T = Wfin^T @ X^T  (N=128 -> 4 col-slices x 2 row-halves) ----
  {
    const int mf = (wv & 3) * 32;   // Wfin col slice
    const int nf = (wv >> 2);       // row half
    const int rdF = (nf*32 + lo)*LDSP + hi*8;
    bf16x8 wf[16];
#pragma unroll
    for (int ks=0; ks<16; ks++)
      wf[ks] = load_wfrag_f(Wfin, OUTD, ks*16 + hi*8, mf + lo, false);
    f32x16 acc = load_bias(bfin, mf, hi);
#pragma unroll
    for (int ks=0; ks<16; ks++){
      bf16x8 bfr = *(const bf16x8*)(Xb + rdF + ks*16);
      acc = MFMA(wf[ks], bfr, acc);
    }
    float* orow = out + (size_t)(row0 + nf*32 + lo)*OUTD;
#pragma unroll
    for (int q=0;q<4;q++){
      float4 v = make_float4(acc[4*q], acc[4*q+1], acc[4*q+2], acc[4*q+3]);
      *(float4*)(orow + mf + 8*q + 4*hi) = v;
    }
  }
}

extern "C" void kernel_launch(void* const* d_in, const int* in_sizes, int n_in,
                              void* d_out, int out_size, void* d_ws, size_t ws_size,
                              hipStream_t stream) {
  (void)in_sizes; (void)n_in; (void)d_ws; (void)ws_size; (void)out_size;
  const float* x     = (const float*)d_in[0];
  const float* Winit = (const float*)d_in[1];
  const float* binit = (const float*)d_in[2];
  const float* Wg1   = (const float*)d_in[3];
  const float* bg1   = (const float*)d_in[4];
  const float* Wg2   = (const float*)d_in[5];
  const float* bg2   = (const float*)d_in[6];
  const float* Wfin  = (const float*)d_in[7];
  const float* bfin  = (const float*)d_in[8];
  float* out = (float*)d_out;
  irn_kernel<<<dim3(B_TOTAL/MTILE), dim3(512), 0, stream>>>(
      x, Winit, binit, Wg1, bg1, Wg2, bg2, Wfin, bfin, out);
}

// Round 5
// 777.463 us; speedup vs baseline: 1.7289x; 1.7289x over previous
//
#include <hip/hip_runtime.h>
#include <hip/hip_bf16.h>

// Fused InverseResNet. Round 5: weights pinned in AGPRs via inline asm.
// Diagnosis chain: R2-R4 all spilled because LLVM won't place long-lived MFMA
// A-operand arrays in AGPRs; 8-wave WG caps unified regs at 256/wave (128 arch
// + 128 acc). So: w1f -> a0..a63, -w2f -> a64..a127 (v_accvgpr_write, once per
// block), MFMA via asm reading a[k:k+3], full AGPR clobber lists everywhere so
// the compiler never touches a0-a127. Arch side ~90 regs: acc 32, packed y 16,
// packed b1 8, addresses/frags. Manual hazard fences (s_nop) around asm MFMAs.

#define B_TOTAL 65536
#define LATENT  128
#define HIDDEN  256
#define OUTD    128
#define NBLOCKS 4
#define NITER   10
#define MTILE   64
#define LDSP    264   // row stride (elems); 528 B rows, 16B-aligned, b128-read conflict-free

typedef unsigned short u16;
typedef unsigned int   u32;
typedef u16    u16x4  __attribute__((ext_vector_type(4)));
typedef u16    u16x8  __attribute__((ext_vector_type(8)));
typedef __bf16 bf16x8 __attribute__((ext_vector_type(8)));
typedef float  f32x16 __attribute__((ext_vector_type(16)));

__device__ inline u16 f2b(float f){ __bf16 h=(__bf16)f; return __builtin_bit_cast(u16,h); }
__device__ inline float up_lo(u32 u){ return __builtin_bit_cast(float, u<<16); }
__device__ inline float up_hi(u32 u){ return __builtin_bit_cast(float, u & 0xffff0000u); }
__device__ inline u32 pk2(float lo, float hi){ return (u32)f2b(lo) | ((u32)f2b(hi)<<16); }

// All 128 weight AGPRs, clobbered on every asm touching them.
#define AGC \
 "a0","a1","a2","a3","a4","a5","a6","a7","a8","a9","a10","a11","a12","a13","a14","a15", \
 "a16","a17","a18","a19","a20","a21","a22","a23","a24","a25","a26","a27","a28","a29","a30","a31", \
 "a32","a33","a34","a35","a36","a37","a38","a39","a40","a41","a42","a43","a44","a45","a46","a47", \
 "a48","a49","a50","a51","a52","a53","a54","a55","a56","a57","a58","a59","a60","a61","a62","a63", \
 "a64","a65","a66","a67","a68","a69","a70","a71","a72","a73","a74","a75","a76","a77","a78","a79", \
 "a80","a81","a82","a83","a84","a85","a86","a87","a88","a89","a90","a91","a92","a93","a94","a95", \
 "a96","a97","a98","a99","a100","a101","a102","a103","a104","a105","a106","a107","a108","a109","a110","a111", \
 "a112","a113","a114","a115","a116","a117","a118","a119","a120","a121","a122","a123","a124","a125","a126","a127"

// Load one K-step weight fragment (8 rows of col colw) into 4 literal AGPRs.
#define LOADW(P, KS, NEG, A0,A1,A2,A3) { \
  const float* _w = (P) + (size_t)((KS)*16 + hi*8)*HIDDEN + colw; \
  float _v0=_w[0], _v1=_w[HIDDEN], _v2=_w[2*HIDDEN], _v3=_w[3*HIDDEN]; \
  float _v4=_w[4*HIDDEN], _v5=_w[5*HIDDEN], _v6=_w[6*HIDDEN], _v7=_w[7*HIDDEN]; \
  if (NEG){_v0=-_v0;_v1=-_v1;_v2=-_v2;_v3=-_v3;_v4=-_v4;_v5=-_v5;_v6=-_v6;_v7=-_v7;} \
  u32 _d0=pk2(_v0,_v1), _d1=pk2(_v2,_v3), _d2=pk2(_v4,_v5), _d3=pk2(_v6,_v7); \
  asm volatile("v_accvgpr_write_b32 a" #A0 ", %0\n\t" \
               "v_accvgpr_write_b32 a" #A1 ", %1\n\t" \
               "v_accvgpr_write_b32 a" #A2 ", %2\n\t" \
               "v_accvgpr_write_b32 a" #A3 ", %3" \
               :: "v"(_d0),"v"(_d1),"v"(_d2),"v"(_d3) : AGC); }

// One K-step: 2 LDS b128 reads (rows lo, 32+lo) + 2 MFMAs from AGPR weights.
#define STEP(SRC, KS, A0, A3) { \
  bf16x8 _b0 = *(const bf16x8*)((SRC) + rdA0 + (KS)*16); \
  bf16x8 _b1 = *(const bf16x8*)((SRC) + rdA1 + (KS)*16); \
  asm volatile("v_mfma_f32_32x32x16_bf16 %0, a[" #A0 ":" #A3 "], %1, %0" \
               : "+v"(acc0) : "v"(_b0) : AGC); \
  asm volatile("v_mfma_f32_32x32x16_bf16 %0, a[" #A0 ":" #A3 "], %1, %0" \
               : "+v"(acc1) : "v"(_b1) : AGC); }

// MFMA -> VALU-read hazard fence; acc as +v operands pins ordering.
#define ACCFENCE asm volatile("s_nop 7\n\ts_nop 7\n\ts_nop 7" : "+v"(acc0), "+v"(acc1))

// Intrinsic MFMA (used only in init/final GEMMs, outside the AGPR region).
#define MFMA_I(a,b,c) __builtin_amdgcn_mfma_f32_32x32x16_bf16(a,b,c,0,0,0)

__device__ inline bf16x8 load_wfrag_f(const float* __restrict__ W, int ldw, int krow0,
                                      int col){
  bf16x8 r;
#pragma unroll
  for (int j=0;j<8;j++) r[j] = (__bf16)W[(size_t)(krow0+j)*ldw + col];
  return r;
}

// Store C^T tile to row-major LDS: row = rowbase+lo, cols nb+8q+4hi+{0..3}.
__device__ inline void store_tile(u16* __restrict__ dst, int row_elem, int nb, int hi,
                                  const f32x16 a, bool relu){
#pragma unroll
  for (int q=0;q<4;q++){
    u16x4 p;
#pragma unroll
    for (int i=0;i<4;i++){
      float v = a[4*q+i];
      if (relu) v = v > 0.f ? v : 0.f;
      p[i] = f2b(v);
    }
    *(u16x4*)(dst + row_elem + nb + 8*q + 4*hi) = p;
  }
}

__global__
__attribute__((amdgpu_flat_work_group_size(512,512)))
void irn_kernel(const float* __restrict__ x,
                const float* __restrict__ Winit, const float* __restrict__ binit,
                const float* __restrict__ Wg1,   const float* __restrict__ bg1,
                const float* __restrict__ Wg2,   const float* __restrict__ bg2,
                const float* __restrict__ Wfin,  const float* __restrict__ bfin,
                float* __restrict__ out)
{
  __shared__ u16 Xb[MTILE*LDSP];
  __shared__ u16 Hb[MTILE*LDSP];

  const int tid = threadIdx.x;
  const int wv  = tid >> 6;      // wave 0..7 -> 32-col slice of HIDDEN
  const int ln  = tid & 63;
  const int lo  = ln & 31;
  const int hi  = ln >> 5;
  const int row0 = blockIdx.x * MTILE;
  const int nb   = wv * 32;
  const int colw = nb + lo;      // this lane's weight column

  // ---- stage x tile [64 x 128] fp32 -> bf16 into Xb ----
  {
    const int r  = tid >> 3;
    const int c0 = (tid & 7) * 16;
    const float4* src = (const float4*)(x + (size_t)(row0 + r)*LATENT + c0);
    u16x8 p0, p1;
#pragma unroll
    for (int i=0;i<2;i++){
      float4 a = src[i*2], b = src[i*2+1];
      u16x8& p = i ? p1 : p0;
      p[0]=f2b(a.x); p[1]=f2b(a.y); p[2]=f2b(a.z); p[3]=f2b(a.w);
      p[4]=f2b(b.x); p[5]=f2b(b.y); p[6]=f2b(b.z); p[7]=f2b(b.w);
    }
    u16* dst = Xb + r*LDSP + c0;
    *(u16x8*)(dst)   = p0;
    *(u16x8*)(dst+8) = p1;
  }

  const int rdA0 = lo*LDSP + hi*8;        // activation rows lo / 32+lo
  const int rdA1 = (32+lo)*LDSP + hi*8;

  u32 yp0[8], yp1[8];   // packed bf16x2 y (later y-b2), C^T reg order
  u32 b1p[8];           // packed b1

  __syncthreads();

  // ---- initial GEMM: h^T = Winit^T @ x^T (K=128), intrinsics (pre-AGPR region) ----
  {
    bf16x8 wf[8];
#pragma unroll
    for (int ks=0; ks<8; ks++)
      wf[ks] = load_wfrag_f(Winit, HIDDEN, ks*16 + hi*8, colw);
    f32x16 acc0, acc1;
#pragma unroll
    for (int r=0;r<16;r++){
      float bv = binit[nb + (r&3) + 8*(r>>2) + 4*hi];
      acc0[r]=bv; acc1[r]=bv;
    }
#pragma unroll
    for (int ks=0; ks<8; ks++){
      bf16x8 b0 = *(const bf16x8*)(Xb + rdA0 + ks*16);
      bf16x8 b1 = *(const bf16x8*)(Xb + rdA1 + ks*16);
      acc0=MFMA_I(wf[ks], b0, acc0);
      acc1=MFMA_I(wf[ks], b1, acc1);
    }
    __syncthreads();
    store_tile(Xb, (0 +lo)*LDSP, nb, hi, acc0, false);
    store_tile(Xb, (32+lo)*LDSP, nb, hi, acc1, false);
#pragma unroll
    for (int i=0;i<8;i++){
      yp0[i] = pk2(acc0[2*i], acc0[2*i+1]);
      yp1[i] = pk2(acc1[2*i], acc1[2*i+1]);
    }
    __syncthreads();
  }

  // ---- 4 blocks x 10 fixed-point iterations ----
#pragma unroll 1
  for (int b=0; b<NBLOCKS; b++){
    const float* W1p = Wg1 + (size_t)b*HIDDEN*HIDDEN;
    const float* W2p = Wg2 + (size_t)b*HIDDEN*HIDDEN;

    // W1 -> a0..a63
    LOADW(W1p, 0,0,  0,1,2,3)    LOADW(W1p, 1,0,  4,5,6,7)
    LOADW(W1p, 2,0,  8,9,10,11)  LOADW(W1p, 3,0,  12,13,14,15)
    LOADW(W1p, 4,0,  16,17,18,19) LOADW(W1p, 5,0,  20,21,22,23)
    LOADW(W1p, 6,0,  24,25,26,27) LOADW(W1p, 7,0,  28,29,30,31)
    LOADW(W1p, 8,0,  32,33,34,35) LOADW(W1p, 9,0,  36,37,38,39)
    LOADW(W1p,10,0,  40,41,42,43) LOADW(W1p,11,0,  44,45,46,47)
    LOADW(W1p,12,0,  48,49,50,51) LOADW(W1p,13,0,  52,53,54,55)
    LOADW(W1p,14,0,  56,57,58,59) LOADW(W1p,15,0,  60,61,62,63)
    // -W2 -> a64..a127
    LOADW(W2p, 0,1,  64,65,66,67)   LOADW(W2p, 1,1,  68,69,70,71)
    LOADW(W2p, 2,1,  72,73,74,75)   LOADW(W2p, 3,1,  76,77,78,79)
    LOADW(W2p, 4,1,  80,81,82,83)   LOADW(W2p, 5,1,  84,85,86,87)
    LOADW(W2p, 6,1,  88,89,90,91)   LOADW(W2p, 7,1,  92,93,94,95)
    LOADW(W2p, 8,1,  96,97,98,99)   LOADW(W2p, 9,1,  100,101,102,103)
    LOADW(W2p,10,1,  104,105,106,107) LOADW(W2p,11,1,  108,109,110,111)
    LOADW(W2p,12,1,  112,113,114,115) LOADW(W2p,13,1,  116,117,118,119)
    LOADW(W2p,14,1,  120,121,122,123) LOADW(W2p,15,1,  124,125,126,127)
    asm volatile("s_nop 3" :::);   // accvgpr_write -> MFMA-read wait states

    { // biases: pack b1; fold b2 into packed y (y <- y - b2), both exact-bf16 stores
      const float* b1g = bg1 + b*HIDDEN;
      const float* b2g = bg2 + b*HIDDEN;
#pragma unroll
      for (int i=0;i<8;i++){
        const int c = nb + (2*i&3) + 8*(2*i>>2) + 4*hi;
        b1p[i] = pk2(b1g[c], b1g[c+1]);
        yp0[i] = pk2(up_lo(yp0[i]) - b2g[c], up_hi(yp0[i]) - b2g[c+1]);
        yp1[i] = pk2(up_lo(yp1[i]) - b2g[c], up_hi(yp1[i]) - b2g[c+1]);
      }
    }

#pragma unroll 1
    for (int it=0; it<NITER; it++){
      { // phase 1: H = relu(X @ W1 + b1)
        f32x16 acc0, acc1;
#pragma unroll
        for (int i=0;i<8;i++){
          acc0[2*i]=up_lo(b1p[i]); acc0[2*i+1]=up_hi(b1p[i]);
          acc1[2*i]=acc0[2*i];     acc1[2*i+1]=acc0[2*i+1];
        }
        STEP(Xb, 0, 0,3)   STEP(Xb, 1, 4,7)   STEP(Xb, 2, 8,11)  STEP(Xb, 3, 12,15)
        STEP(Xb, 4, 16,19) STEP(Xb, 5, 20,23) STEP(Xb, 6, 24,27) STEP(Xb, 7, 28,31)
        STEP(Xb, 8, 32,35) STEP(Xb, 9, 36,39) STEP(Xb,10, 40,43) STEP(Xb,11, 44,47)
        STEP(Xb,12, 48,51) STEP(Xb,13, 52,55) STEP(Xb,14, 56,59) STEP(Xb,15, 60,63)
        ACCFENCE;
        store_tile(Hb, (0 +lo)*LDSP, nb, hi, acc0, true);
        store_tile(Hb, (32+lo)*LDSP, nb, hi, acc1, true);
      }
      __syncthreads();
      { // phase 2: Xnew = (y - b2) + H @ (-W2)
        f32x16 acc0, acc1;
#pragma unroll
        for (int i=0;i<8;i++){
          acc0[2*i]=up_lo(yp0[i]); acc0[2*i+1]=up_hi(yp0[i]);
          acc1[2*i]=up_lo(yp1[i]); acc1[2*i+1]=up_hi(yp1[i]);
        }
        STEP(Hb, 0, 64,67)   STEP(Hb, 1, 68,71)   STEP(Hb, 2, 72,75)   STEP(Hb, 3, 76,79)
        STEP(Hb, 4, 80,83)   STEP(Hb, 5, 84,87)   STEP(Hb, 6, 88,91)   STEP(Hb, 7, 92,95)
        STEP(Hb, 8, 96,99)   STEP(Hb, 9, 100,103) STEP(Hb,10, 104,107) STEP(Hb,11, 108,111)
        STEP(Hb,12, 112,115) STEP(Hb,13, 116,119) STEP(Hb,14, 120,123) STEP(Hb,15, 124,127)
        ACCFENCE;
        store_tile(Xb, (0 +lo)*LDSP, nb, hi, acc0, false);
        store_tile(Xb, (32+lo)*LDSP, nb, hi, acc1, false);
        if (it == NITER-1){
#pragma unroll
          for (int i=0;i<8;i++){
            yp0[i] = pk2(acc0[2*i], acc0[2*i+1]);
            yp1[i] = pk2(acc1[2*i], acc1[2*i+1]);
          }
        }
      }
      __syncthreads();
    }
  }

  // ---- final GEMM: out^T = Wfin^T @ X^T (intrinsics, post-AGPR region) ----
  {
    const int mf = (wv & 3) * 32;   // Wfin col slice
    const int nf = (wv >> 2);       // row half
    const int rdF = (nf*32 + lo)*LDSP + hi*8;
    bf16x8 wf[16];
#pragma unroll
    for (int ks=0; ks<16; ks++)
      wf[ks] = load_wfrag_f(Wfin, OUTD, ks*16 + hi*8, mf + lo);
    f32x16 acc;
#pragma unroll
    for (int r=0;r<16;r++) acc[r] = bfin[mf + (r&3) + 8*(r>>2) + 4*hi];
#pragma unroll
    for (int ks=0; ks<16; ks++){
      bf16x8 bfr = *(const bf16x8*)(Xb + rdF + ks*16);
      acc = MFMA_I(wf[ks], bfr, acc);
    }
    float* orow = out + (size_t)(row0 + nf*32 + lo)*OUTD;
#pragma unroll
    for (int q=0;q<4;q++){
      float4 v = make_float4(acc[4*q], acc[4*q+1], acc[4*q+2], acc[4*q+3]);
      *(float4*)(orow + mf + 8*q + 4*hi) = v;
    }
  }
}

extern "C" void kernel_launch(void* const* d_in, const int* in_sizes, int n_in,
                              void* d_out, int out_size, void* d_ws, size_t ws_size,
                              hipStream_t stream) {
  (void)in_sizes; (void)n_in; (void)d_ws; (void)ws_size; (void)out_size;
  const float* x     = (const float*)d_in[0];
  const float* Winit = (const float*)d_in[1];
  const float* binit = (const float*)d_in[2];
  const float* Wg1   = (const float*)d_in[3];
  const float* bg1   = (const float*)d_in[4];
  const float* Wg2   = (const float*)d_in[5];
  const float* bg2   = (const float*)d_in[6];
  const float* Wfin  = (const float*)d_in[7];
  const float* bfin  = (const float*)d_in[8];
  float* out = (float*)d_out;
  irn_kernel<<<dim3(B_TOTAL/MTILE), dim3(512), 0, stream>>>(
      x, Winit, binit, Wg1, bg1, Wg2, bg2, Wfin, bfin, out);
}